// Round 7
// baseline (60.417 us; speedup 1.0000x reference)
//
#include <hip/hip_runtime.h>
#include <math.h>

// Problem constants (fixed by the reference)
#define B_    16
#define F_    32
#define NP_   128   // rows per (b,f) panel
#define D_    512
#define P_    16
#define E_    32    // 2*P outputs per row
#define QK    128   // K-quarter per thread
#define NKC   8     // kc steps per quarter (16 floats each)
#define LROW  33    // padded row stride in epilogue LDS (bank-conflict-free)
#define PQ    (NP_ * LROW)   // floats per quarter region

// 512 threads = 128 rows x 4 K-quarters. Grid 512 -> 2 blocks/CU, 4 waves/SIMD.
// Main loop: NO barriers, NO LDS. Each thread streams its (row, quarter) slice
// global->VGPR once (each lane consumes its own 64B line per kc step) and
// accumulates all 32 e's in registers against s_loaded W (scalar pipe).
__global__ __launch_bounds__(512, 4)
void pd_kernel(const float* __restrict__ ts,
               const float* __restrict__ W,
               const float* __restrict__ bias,
               float* __restrict__ out, int T)
{
    __shared__ float part[4 * PQ];   // 67.6 KB -> still 2 blocks/CU (<=80 KB)

    const int tid = threadIdx.x;
    const int n   = tid & 127;                                   // row in panel
    const int u   = __builtin_amdgcn_readfirstlane(tid >> 7);    // quarter 0..3 (wave-uniform)

    // XCD-aware block-id encoding (proven: WRITE_SIZE at ideal ~4.1 MB)
    const int d = blockIdx.x;
    const int b = (d & 7) | ((d >> 8) << 3);
    const int f = (d >> 3) & 31;
    const float* __restrict__ arow  = ts + ((size_t)b * F_ + f) * NP_ * D_
                                        + (size_t)n * D_ + u * QK;
    const float* __restrict__ wbase = W + u * QK;   // uniform base

    float acc[E_];
#pragma unroll
    for (int e = 0; e < E_; ++e) acc[e] = 0.f;

    // ---- main loop: 8 kc steps x (load 16 floats of own row) x (32 e FMA-16)
#pragma unroll 2
    for (int kc = 0; kc < NKC; ++kc) {
        const float4* ap = (const float4*)(arow + kc * 16);
        const float4 r0 = ap[0];
        const float4 r1 = ap[1];
        const float4 r2 = ap[2];
        const float4 r3 = ap[3];
#pragma unroll
        for (int e = 0; e < E_; ++e) {
            // 16 consecutive wave-uniform floats -> s_load_dwordx16 (R6 idiom)
            const float* we = wbase + __builtin_amdgcn_readfirstlane(e * D_ + kc * 16);
            float s0 = r0.x * we[0]  + r0.y * we[1]  + r0.z * we[2]  + r0.w * we[3];
            float s1 = r1.x * we[4]  + r1.y * we[5]  + r1.z * we[6]  + r1.w * we[7];
            float s2 = r2.x * we[8]  + r2.y * we[9]  + r2.z * we[10] + r2.w * we[11];
            float s3 = r3.x * we[12] + r3.y * we[13] + r3.z * we[14] + r3.w * we[15];
            acc[e] += (s0 + s1) + (s2 + s3);
        }
    }

    // ---- epilogue 1: write quarter-partials to LDS (stride-33: (n+e)%32
    //      across 64 consecutive-n lanes = 2-way aliasing = free)
#pragma unroll
    for (int e = 0; e < E_; ++e) part[u * PQ + n * LROW + e] = acc[e];
    __syncthreads();

    // ---- epilogue 2: reduce 4 quarters, +bias, exp for sigma half.
    // thread -> (row n2, e-octet eg). Each part[0] slot is read and written
    // by the SAME thread -> in-place is race-free.
    {
        const int n2 = tid & 127;
        const int eg = tid >> 7;
#pragma unroll
        for (int j = 0; j < 8; ++j) {
            const int e = eg * 8 + j;
            float s = part[0 * PQ + n2 * LROW + e]
                    + part[1 * PQ + n2 * LROW + e]
                    + part[2 * PQ + n2 * LROW + e]
                    + part[3 * PQ + n2 * LROW + e];
            s += bias[e];
            if (e >= P_) s = fmaxf(expf(s), 1e-6f);   // sigma half (wave-uniform)
            part[n2 * LROW + e] = s;
        }
    }
    __syncthreads();

    // ---- epilogue 3: gather. out[b,t,f] = sum_{n: t-8n in [0,16)} raw[n][.] / cnt
    const int TF = T * F_;
    const size_t halfoff = (size_t)B_ * TF;
    for (int item = tid; item < 2 * T; item += 512) {
        const int half = (item >= T) ? 1 : 0;
        const int t    = item - half * T;
        const int nmax = min(NP_ - 1, t >> 3);
        const int nmin = (t > 8) ? ((t - 8) >> 3) : 0;
        float sum = 0.f;
        const int cnt = nmax - nmin + 1;
        for (int nn = nmin; nn <= nmax; ++nn)
            sum += part[nn * LROW + (half << 4) + (t - (nn << 3))];
        const float r = (cnt > 0) ? sum / (float)cnt : 0.f;
        out[(size_t)half * halfoff + (size_t)b * TF + (size_t)t * F_ + f] = r;
    }
}

extern "C" void kernel_launch(void* const* d_in, const int* in_sizes, int n_in,
                              void* d_out, int out_size, void* d_ws, size_t ws_size,
                              hipStream_t stream)
{
    const float* ts   = (const float*)d_in[0];
    const float* W    = (const float*)d_in[1];
    const float* bias = (const float*)d_in[2];
    float* out = (float*)d_out;

    // T derived on host from out_size = 2 * B * T * F
    const int T = out_size / (2 * B_ * F_);

    dim3 grid(B_ * F_);   // 512 blocks, one per (b, f), XCD-encoded id
    dim3 block(512);
    pd_kernel<<<grid, block, 0, stream>>>(ts, W, bias, out, T);
}

// Round 8
// 49.528 us; speedup vs baseline: 1.2199x; 1.2199x over previous
//
#include <hip/hip_runtime.h>
#include <math.h>

// Problem constants (fixed by the reference)
#define B_   16
#define F_   32
#define NP_  128   // Np = FNP / F = 4096/32
#define D_   512
#define P_   16
#define KC   64            // K-chunk in floats (256 B per row per chunk)
#define NCH  (D_ / KC)     // 8 chunks

// 512 threads = 8 waves; grid 512 on 256 CUs -> 2 blocks/CU, 16 waves/CU.
// R6 structure (best: 77us dispatch) + T3/T4 counted-vmcnt barriers:
// stage loads stay IN FLIGHT across the barrier (no vmcnt(0) drain).
__global__ __launch_bounds__(512, 4)
void pd_kernel(const float* __restrict__ ts,
               const float* __restrict__ W,
               const float* __restrict__ bias,
               float* __restrict__ out, int T)
{
    // 2 buffers x 128 rows x 64 floats = 64 KB; buffer 0 reused by epilogue
    __shared__ float smem[2 * NP_ * KC];

    const int tid  = threadIdx.x;
    const int lane = tid & 63;
    // wave w -> e's 4w..4w+3 (wave-uniform; forces s_load for W)
    const int e0   = __builtin_amdgcn_readfirstlane((tid >> 6) << 2);

    // XCD-aware block-id encoding (proven: WRITE_SIZE at ideal ~4.1 MB)
    const int d = blockIdx.x;
    const int b = (d & 7) | ((d >> 8) << 3);
    const int f = (d >> 3) & 31;
    const float* __restrict__ tsb = ts + ((size_t)b * F_ + f) * NP_ * D_;

    float acc[2][4];
#pragma unroll
    for (int j = 0; j < 2; ++j)
#pragma unroll
        for (int eo = 0; eo < 4; ++eo) acc[j][eo] = 0.f;

    // Stage chunk cc into buffer cc&1. Swizzle qg = ql ^ (row & 15):
    // bijective per row, proven conflict-free (R5: 4.39M -> 194K).
    auto STAGE = [&](int cc) {
        const int k0 = cc * KC;
        float* dstb = smem + (cc & 1) * (NP_ * KC);
#pragma unroll
        for (int it = 0; it < 4; ++it) {
            int slot = it * 512 + tid;       // 0..2047 16B-slots
            int rr = slot >> 4;
            int ql = slot & 15;
            int qg = ql ^ (rr & 15);
            const float* src = tsb + rr * D_ + k0 + (qg << 2);
            __builtin_amdgcn_global_load_lds(
                (const __attribute__((address_space(1))) unsigned int*)src,
                (__attribute__((address_space(3))) unsigned int*)&dstb[slot << 2],
                16, 0, 0);
        }
    };

    STAGE(0);                       // 4 loads in flight

    const int sw = lane & 15;       // rows lane and lane+64 share (lane & 15)

    for (int c = 0; c < NCH; ++c) {
        // barrier alpha: every wave has finished compute(c-1), i.e. done
        // reading buf[(c+1)&1] -> safe for stage(c+1) to overwrite it.
        asm volatile("s_barrier" ::: "memory");

        if (c + 1 < NCH) {
            STAGE(c + 1);           // outstanding: stage(c) 4 + stage(c+1) 4
            // wait ONLY for stage(c); stage(c+1) stays in flight across
            // the barrier (the counted-vmcnt trick; no full drain).
            asm volatile("s_waitcnt vmcnt(4)\n\ts_barrier" ::: "memory");
        } else {
            asm volatile("s_waitcnt vmcnt(0)\n\ts_barrier" ::: "memory");
        }
        __builtin_amdgcn_sched_barrier(0);   // don't hoist ds_reads above wait

        // ---- compute(c): 2 rows (lane, lane+64) x 4 e's; W hoisted to SGPRs
        // as merged s_load_dwordx16 per quarter (R6 idiom).
        const float* row0 = smem + (c & 1) * (NP_ * KC) + lane * KC;
        const float* row1 = row0 + 64 * KC;
        const int kb = c * KC;
#pragma unroll
        for (int u = 0; u < 4; ++u) {
            float wv[4][16];
#pragma unroll
            for (int eo = 0; eo < 4; ++eo) {
                const float* we = W + __builtin_amdgcn_readfirstlane(
                                        (e0 + eo) * D_ + kb + u * 16);
#pragma unroll
                for (int jj = 0; jj < 16; ++jj) wv[eo][jj] = we[jj];
            }
#pragma unroll
            for (int kq = 0; kq < 4; ++kq) {
                const int q = (u << 2) + kq;
                const int off = ((q ^ sw) << 2);
                const float4 a0 = *(const float4*)(row0 + off);
                const float4 a1 = *(const float4*)(row1 + off);
#pragma unroll
                for (int eo = 0; eo < 4; ++eo) {
                    const float w0 = wv[eo][kq * 4 + 0];
                    const float w1 = wv[eo][kq * 4 + 1];
                    const float w2 = wv[eo][kq * 4 + 2];
                    const float w3 = wv[eo][kq * 4 + 3];
                    acc[0][eo] += a0.x * w0 + a0.y * w1 + a0.z * w2 + a0.w * w3;
                    acc[1][eo] += a1.x * w0 + a1.y * w1 + a1.z * w2 + a1.w * w3;
                }
            }
        }
    }

    // ---- epilogue 1: raw -> LDS (padded stride 33; only buf0 region is
    // written [4224 floats], compute(7) read buf1 -> no race with laggards)
#pragma unroll
    for (int j = 0; j < 2; ++j) {
        const int n = lane + (j << 6);
#pragma unroll
        for (int eo = 0; eo < 4; ++eo) {
            const int e = e0 + eo;
            float v = acc[j][eo] + bias[e];
            if (e >= P_) v = fmaxf(expf(v), 1e-6f);   // sigma half (wave-uniform)
            smem[n * 33 + e] = v;
        }
    }
    __syncthreads();

    // ---- epilogue 2: gather. out[b,t,f] = sum_{n: t-8n in [0,16)} raw / cnt
    const int TF = T * F_;
    const size_t halfoff = (size_t)B_ * TF;
    for (int item = tid; item < 2 * T; item += 512) {
        const int half = (item >= T) ? 1 : 0;
        const int t    = item - half * T;
        const int nmax = min(NP_ - 1, t >> 3);
        const int nmin = (t > 8) ? ((t - 8) >> 3) : 0;
        float sum = 0.f;
        const int cnt = nmax - nmin + 1;
        for (int nn = nmin; nn <= nmax; ++nn)
            sum += smem[nn * 33 + (half << 4) + (t - (nn << 3))];
        const float r = (cnt > 0) ? sum / (float)cnt : 0.f;
        out[(size_t)half * halfoff + (size_t)b * TF + (size_t)t * F_ + f] = r;
    }
}

extern "C" void kernel_launch(void* const* d_in, const int* in_sizes, int n_in,
                              void* d_out, int out_size, void* d_ws, size_t ws_size,
                              hipStream_t stream)
{
    const float* ts   = (const float*)d_in[0];
    const float* W    = (const float*)d_in[1];
    const float* bias = (const float*)d_in[2];
    float* out = (float*)d_out;

    // T derived on host from out_size = 2 * B * T * F
    const int T = out_size / (2 * B_ * F_);

    dim3 grid(B_ * F_);   // 512 blocks, one per (b, f), XCD-encoded id
    dim3 block(512);
    pd_kernel<<<grid, block, 0, stream>>>(ts, W, bias, out, T);
}

// Round 9
// 42.469 us; speedup vs baseline: 1.4226x; 1.1662x over previous
//
#include <hip/hip_runtime.h>
#include <math.h>

// Problem constants (fixed by the reference)
#define B_   16
#define F_   32
#define NP_  128   // rows per (b,f) panel
#define D_   512
#define P_   16
#define KC   64            // K-chunk in floats (256 B per row per chunk)
#define NCH  (D_ / KC)     // 8 chunks = 4 MFMA k-steps (K=16) each

typedef __attribute__((ext_vector_type(8)))  short  short8;   // 8 bf16 = 4 VGPR
typedef __attribute__((ext_vector_type(16))) float  floatx16; // 32x32 acc

union Frag { short8 v; unsigned int u[4]; };

__device__ inline unsigned int cvt_pk_bf16(float lo, float hi) {
    unsigned int r;
    asm volatile("v_cvt_pk_bf16_f32 %0, %1, %2" : "=v"(r) : "v"(lo), "v"(hi));
    return r;   // low 16 = bf16(lo), high 16 = bf16(hi)
}

// 512 threads = 8 waves = 4 M-tiles(32 rows) x 2 K-parities; 2 blocks/CU.
// GEMM on matrix cores (bf16 in, fp32 acc); A staged fp32 via global_load_lds
// (proven swizzle), converted to bf16 at ds_read time; B (W^T) fragments for
// this wave's 16 k-steps preloaded into 64 VGPRs once -> NO SMEM in main loop.
__global__ __launch_bounds__(512, 4)
void pd_kernel(const float* __restrict__ ts,
               const float* __restrict__ W,
               const float* __restrict__ bias,
               float* __restrict__ out, int T)
{
    __shared__ float smem[2 * NP_ * KC];   // 64 KB; buf0 region reused by epilogue

    const int tid  = threadIdx.x;
    const int lane = tid & 63;
    const int wave = tid >> 6;       // 0..7
    const int mt   = wave & 3;       // M-tile: rows 32*mt .. +31
    const int p    = wave >> 2;      // k-step parity (0/1)

    // XCD-aware block-id encoding (proven: WRITE_SIZE at ideal ~4.1 MB)
    const int d = blockIdx.x;
    const int b = (d & 7) | ((d >> 8) << 3);
    const int f = (d >> 3) & 31;
    const float* __restrict__ tsb = ts + ((size_t)b * F_ + f) * NP_ * D_;

    // Stage chunk cc into buffer cc&1. LDS slot (row rr, quad ql) holds global
    // quad ql^(rr&15) — bijective, read-side uses same XOR (R5: conflict-free).
    auto STAGE = [&](int cc) {
        const int k0 = cc * KC;
        float* dstb = smem + (cc & 1) * (NP_ * KC);
#pragma unroll
        for (int it = 0; it < 4; ++it) {
            int slot = it * 512 + tid;       // 0..2047 16B-slots
            int rr = slot >> 4;
            int ql = slot & 15;
            int qg = ql ^ (rr & 15);
            const float* src = tsb + rr * D_ + k0 + (qg << 2);
            __builtin_amdgcn_global_load_lds(
                (const __attribute__((address_space(1))) unsigned int*)src,
                (__attribute__((address_space(3))) unsigned int*)&dstb[slot << 2],
                16, 0, 0);
        }
    };

    STAGE(0);

    // ---- B preload: this wave's 16 k-steps, s = c*4 + p + 2j (c=0..7, j=0..1).
    // B[k][n]=W[n][k]: lane holds e=lane&31, k-half kh=lane>>5 (8 consecutive k).
    const int e_b = lane & 31;
    const int kh  = lane >> 5;
    Frag bf[NCH][2];
    {
        const float* wb = W + (size_t)e_b * D_ + kh * 8;
#pragma unroll
        for (int c = 0; c < NCH; ++c)
#pragma unroll
            for (int j = 0; j < 2; ++j) {
                const int s = c * 4 + p + 2 * j;
                const float4 lo = *(const float4*)(wb + s * 16);
                const float4 hi = *(const float4*)(wb + s * 16 + 4);
                bf[c][j].u[0] = cvt_pk_bf16(lo.x, lo.y);
                bf[c][j].u[1] = cvt_pk_bf16(lo.z, lo.w);
                bf[c][j].u[2] = cvt_pk_bf16(hi.x, hi.y);
                bf[c][j].u[3] = cvt_pk_bf16(hi.z, hi.w);
            }
    }

    floatx16 acc;
#pragma unroll
    for (int r = 0; r < 16; ++r) acc[r] = 0.f;

    // A-frag addressing: row rl=lane&31 of tile mt, k = s*16 + kh*8 + 0..7
    const int rl     = lane & 31;
    const int ldsrow = mt * 32 + rl;
    const int sw16   = ldsrow & 15;

    // ---- main loop (fully unrolled so bf[c][j] stays in registers)
#pragma unroll
    for (int c = 0; c < NCH; ++c) {
        // barrier alpha: all waves done reading buf[(c+1)&1] -> overwrite ok
        asm volatile("s_barrier" ::: "memory");
        if (c + 1 < NCH) {
            STAGE(c + 1);
            // wait only for stage(c) (+older); stage(c+1) stays in flight
            asm volatile("s_waitcnt vmcnt(4)\n\ts_barrier" ::: "memory");
        } else {
            asm volatile("s_waitcnt vmcnt(0)\n\ts_barrier" ::: "memory");
        }
        __builtin_amdgcn_sched_barrier(0);

        const float4* rowp = (const float4*)(smem + (c & 1) * (NP_ * KC) + ldsrow * KC);
#pragma unroll
        for (int j = 0; j < 2; ++j) {
            const int sL = p + 2 * j;           // k-step within chunk (0..3)
            const int q0 = sL * 4 + kh * 2;     // first fp32-quad of lane's 8 k's
            const float4 lo = rowp[q0 ^ sw16];
            const float4 hi = rowp[(q0 + 1) ^ sw16];
            Frag a;
            a.u[0] = cvt_pk_bf16(lo.x, lo.y);
            a.u[1] = cvt_pk_bf16(lo.z, lo.w);
            a.u[2] = cvt_pk_bf16(hi.x, hi.y);
            a.u[3] = cvt_pk_bf16(hi.z, hi.w);
            acc = __builtin_amdgcn_mfma_f32_32x32x16_bf16(a.v, bf[c][j].v, acc, 0, 0, 0);
        }
    }

    // ---- epilogue: merge parity partials in LDS raw[n][e] (stride 33).
    // C mapping (guide, m74/m101): col=lane&31, row=(r&3)+8*(r>>2)+4*(lane>>5).
    if (p == 0) {
#pragma unroll
        for (int r = 0; r < 16; ++r) {
            const int rowl = (r & 3) + 8 * (r >> 2) + 4 * kh;
            smem[(mt * 32 + rowl) * 33 + e_b] = acc[r];
        }
    }
    __syncthreads();
    if (p == 1) {
#pragma unroll
        for (int r = 0; r < 16; ++r) {
            const int rowl = (r & 3) + 8 * (r >> 2) + 4 * kh;
            smem[(mt * 32 + rowl) * 33 + e_b] += acc[r];
        }
    }
    __syncthreads();

    // bias + exp(sigma half): 4096 slots, 8 per thread
#pragma unroll
    for (int jj = 0; jj < 8; ++jj) {
        const int item = tid * 8 + jj;
        const int n = item >> 5;
        const int e = item & 31;
        float v = smem[n * 33 + e] + bias[e];
        if (e >= P_) v = fmaxf(expf(v), 1e-6f);
        smem[n * 33 + e] = v;
    }
    __syncthreads();

    // gather: out[b,t,f] = sum_{n: t-8n in [0,16)} raw[n][.] / cnt
    const int TF = T * F_;
    const size_t halfoff = (size_t)B_ * TF;
    for (int item = tid; item < 2 * T; item += 512) {
        const int half = (item >= T) ? 1 : 0;
        const int t    = item - half * T;
        const int nmax = min(NP_ - 1, t >> 3);
        const int nmin = (t > 8) ? ((t - 8) >> 3) : 0;
        float sum = 0.f;
        const int cnt = nmax - nmin + 1;
        for (int nn = nmin; nn <= nmax; ++nn)
            sum += smem[nn * 33 + (half << 4) + (t - (nn << 3))];
        const float r = (cnt > 0) ? sum / (float)cnt : 0.f;
        out[(size_t)half * halfoff + (size_t)b * TF + (size_t)t * F_ + f] = r;
    }
}

extern "C" void kernel_launch(void* const* d_in, const int* in_sizes, int n_in,
                              void* d_out, int out_size, void* d_ws, size_t ws_size,
                              hipStream_t stream)
{
    const float* ts   = (const float*)d_in[0];
    const float* W    = (const float*)d_in[1];
    const float* bias = (const float*)d_in[2];
    float* out = (float*)d_out;

    // T derived on host from out_size = 2 * B * T * F
    const int T = out_size / (2 * B_ * F_);

    dim3 grid(B_ * F_);   // 512 blocks, one per (b, f), XCD-encoded id
    dim3 block(512);
    pd_kernel<<<grid, block, 0, stream>>>(ts, W, bias, out, T);
}